// Round 1
// baseline (4942.442 us; speedup 1.0000x reference)
//
#include <hip/hip_runtime.h>
#include <hip/hip_bf16.h>
#include <cstdint>
#include <cstddef>

// Problem constants
#define B_ 128
#define T_ 1024
#define D_ 256
#define U_ 256

typedef __bf16 bfrag __attribute__((ext_vector_type(8)));
typedef unsigned short us8 __attribute__((ext_vector_type(8)));
typedef unsigned short us4 __attribute__((ext_vector_type(4)));
typedef float f32x4 __attribute__((ext_vector_type(4)));

__device__ __forceinline__ unsigned short f2bf(float f) {
    unsigned int u = __builtin_bit_cast(unsigned int, f);
    unsigned int r = (u + 0x7fffu + ((u >> 16) & 1u)) >> 16;
    return (unsigned short)r;
}
__device__ __forceinline__ float bf2f(unsigned short h) {
    unsigned int u = ((unsigned int)h) << 16;
    return __builtin_bit_cast(float, u);
}

#if __has_builtin(__builtin_amdgcn_exp2f)
__device__ __forceinline__ float fexp2(float x) { return __builtin_amdgcn_exp2f(x); }
#else
__device__ __forceinline__ float fexp2(float x) { return exp2f(x); }
#endif
#if __has_builtin(__builtin_amdgcn_rcpf)
__device__ __forceinline__ float frcp(float x) { return __builtin_amdgcn_rcpf(x); }
#else
__device__ __forceinline__ float frcp(float x) { return 1.0f / x; }
#endif

__device__ __forceinline__ float sigm(float x) {
    return frcp(1.0f + fexp2(-1.4426950408889634f * x));
}
__device__ __forceinline__ float tanh_(float x) {
    return 1.0f - 2.0f * frcp(1.0f + fexp2(2.8853900817779268f * x));
}

// ---------------------------------------------------------------------------
// Phase 0: xzh[t][col][b] (bf16) = x @ [W_zr | W_h] + [b_zr | b_h]
//   col in [0,512): xz with b_zr; col in [512,768): xh with b_h
// Layout [T][768][B] chosen so the recurrent kernel's C-init loads are
// 8-byte vector loads of 4 consecutive batch elements (matches MFMA C rows).
// Tile: BM=64 rows = 16 batch x 4 timesteps, BN=64, K=256 (8 x BK=32).
// Weights (B operand) preloaded to registers per wave; only A staged in LDS.
// ---------------------------------------------------------------------------
__global__ __launch_bounds__(256) void proj_kernel(
    const float* __restrict__ x, const float* __restrict__ Wzr,
    const float* __restrict__ bzr, const float* __restrict__ Wh,
    const float* __restrict__ bh, unsigned short* __restrict__ xzh)
{
    const int tid  = threadIdx.x;
    const int lane = tid & 63;
    const int wv   = tid >> 6;   // 0..3
    const int wn   = wv & 1;     // n half
    const int wr   = wv >> 1;    // m half
    const int q    = lane >> 4;  // quad
    const int c16  = lane & 15;

    const int bx = blockIdx.x;   // 0..2047
    const int bb = bx >> 8;      // batch block (16 b), 0..7
    const int tb = bx & 255;     // time block (4 t), 0..255
    const int n0 = blockIdx.y * 64;

    __shared__ __align__(16) unsigned short ldsA[64 * 40];  // pad 32->40

    // Preload weight fragments (B operand): 2 n-tiles x 8 k-chunks
    us8 wfrag[2][8];
    float bias[2];
#pragma unroll
    for (int nt = 0; nt < 2; ++nt) {
        int gc = n0 + wn * 32 + nt * 16 + c16;
        const float* Wp; int ldw, cc;
        if (gc < 512) { Wp = Wzr; ldw = 512; cc = gc; }
        else          { Wp = Wh;  ldw = 256; cc = gc - 512; }
        bias[nt] = (gc < 512) ? bzr[gc] : bh[gc - 512];
#pragma unroll
        for (int kk = 0; kk < 8; ++kk) {
            us8 v;
#pragma unroll
            for (int j = 0; j < 8; ++j)
                v[j] = f2bf(Wp[(size_t)(kk * 32 + q * 8 + j) * ldw + cc]);
            wfrag[nt][kk] = v;
        }
    }

    f32x4 acc[2][2] = {};  // [st (m-subtile)][nt]

    // A staging: row ml -> b = bb*16 + (ml&15), t = tb*4 + (ml>>4)
    const int arow  = tid >> 2;        // 0..63
    const int akseg = (tid & 3) * 8;   // 0,8,16,24
    const int ab = bb * 16 + (arow & 15);
    const int at = tb * 4 + (arow >> 4);
    const float* xrow = x + ((size_t)ab * T_ + at) * D_;

#pragma unroll
    for (int k0 = 0; k0 < 256; k0 += 32) {
        const int kk = k0 >> 5;
        us8 av;
        const float* src = xrow + k0 + akseg;
#pragma unroll
        for (int j = 0; j < 8; ++j) av[j] = f2bf(src[j]);
        __syncthreads();
        *reinterpret_cast<us8*>(&ldsA[arow * 40 + akseg]) = av;
        __syncthreads();
#pragma unroll
        for (int st = 0; st < 2; ++st) {
            int ml = (wr * 2 + st) * 16 + c16;   // A row (m = lane&15)
            bfrag af = __builtin_bit_cast(bfrag,
                *reinterpret_cast<const us8*>(&ldsA[ml * 40 + q * 8]));
#pragma unroll
            for (int nt = 0; nt < 2; ++nt) {
                acc[st][nt] = __builtin_amdgcn_mfma_f32_16x16x32_bf16(
                    af, __builtin_bit_cast(bfrag, wfrag[nt][kk]), acc[st][nt], 0, 0, 0);
            }
        }
    }

    // Epilogue: C rows (q*4+i) = batch-local rows; store 4 consecutive b as 8B
#pragma unroll
    for (int st = 0; st < 2; ++st) {
        int t = tb * 4 + wr * 2 + st;
#pragma unroll
        for (int nt = 0; nt < 2; ++nt) {
            int gc = n0 + wn * 32 + nt * 16 + c16;
            us4 ov;
#pragma unroll
            for (int i = 0; i < 4; ++i) ov[i] = f2bf(acc[st][nt][i] + bias[nt]);
            *reinterpret_cast<us4*>(
                &xzh[((size_t)t * 768 + gc) * 128 + bb * 16 + q * 4]) = ov;
        }
    }
}

// ---------------------------------------------------------------------------
// Recurrent kernel: 8 WGs x 512 threads (8 waves). WG g owns batch rows
// [g*16, g*16+16). Recurrent weights live in VGPRs (loaded once, reused
// 1024 steps). h master in LDS fp32; bf16 shadow for MFMA A operand.
// Per step: phase A -> z (512 cols, waves x 64 cols each), sigmoid,
// Z->LDS / Rh->LDS(bf16); barrier; phase B -> s (256 cols, waves x 32),
// tanh + h update; barrier. No inter-WG communication.
// ---------------------------------------------------------------------------
#define HFP 257  // fp32 row pad (bank spread for scalar access)
#define HBP 264  // bf16 row pad (keeps 16B alignment for b128 reads)

__global__ __launch_bounds__(512, 2) void gru_rec(
    const float* __restrict__ Uzr, const float* __restrict__ Uh,
    const unsigned short* __restrict__ xzh, float* __restrict__ out)
{
    const int tid  = threadIdx.x;
    const int lane = tid & 63;
    const int w    = tid >> 6;   // wave 0..7
    const int q    = lane >> 4;
    const int c16  = lane & 15;
    const int g    = blockIdx.x; // batch block

    __shared__ __align__(16) float hf[16 * HFP];            // h master (fp32)
    __shared__ __align__(16) float zf[16 * HFP];            // Z gate (fp32)
    __shared__ __align__(16) unsigned short hb[16 * HBP];   // h (bf16, A-layout)
    __shared__ __align__(16) unsigned short rhb[16 * HBP];  // R*h (bf16, A-layout)

    // ---- one-time weight preload into registers ----
    us8 wA[4][8];  // phase A: cols w*64 + nt*16 + c16 of U_zr  (128 VGPRs)
#pragma unroll
    for (int nt = 0; nt < 4; ++nt) {
        int col = w * 64 + nt * 16 + c16;
#pragma unroll
        for (int kk = 0; kk < 8; ++kk) {
            us8 v;
#pragma unroll
            for (int j = 0; j < 8; ++j)
                v[j] = f2bf(Uzr[(size_t)(kk * 32 + q * 8 + j) * 512 + col]);
            wA[nt][kk] = v;
        }
    }
    us8 wB[2][8];  // phase B: cols w*32 + nt*16 + c16 of U_h   (64 VGPRs)
#pragma unroll
    for (int nt = 0; nt < 2; ++nt) {
        int col = w * 32 + nt * 16 + c16;
#pragma unroll
        for (int kk = 0; kk < 8; ++kk) {
            us8 v;
#pragma unroll
            for (int j = 0; j < 8; ++j)
                v[j] = f2bf(Uh[(size_t)(kk * 32 + q * 8 + j) * 256 + col]);
            wB[nt][kk] = v;
        }
    }

    // ---- init h = 0 ----
    for (int i = tid; i < 16 * HFP; i += 512) hf[i] = 0.0f;
    for (int i = tid; i < 16 * HBP; i += 512) { hb[i] = 0; rhb[i] = 0; }
    __syncthreads();

    const int bbase = g * 16 + q * 4;

    // ---- prefetch t=0 xz/xh fragments ----
    us4 pa[4], pb[2];
#pragma unroll
    for (int nt = 0; nt < 4; ++nt)
        pa[nt] = *reinterpret_cast<const us4*>(
            &xzh[((size_t)0 * 768 + w * 64 + nt * 16 + c16) * 128 + bbase]);
#pragma unroll
    for (int nt = 0; nt < 2; ++nt)
        pb[nt] = *reinterpret_cast<const us4*>(
            &xzh[((size_t)0 * 768 + 512 + w * 32 + nt * 16 + c16) * 128 + bbase]);

#pragma unroll 1
    for (int t = 0; t < T_; ++t) {
        const int tn = (t + 1 < T_) ? (t + 1) : t;
        us4 ca[4], cxh[2];
#pragma unroll
        for (int nt = 0; nt < 4; ++nt) ca[nt] = pa[nt];
#pragma unroll
        for (int nt = 0; nt < 2; ++nt) cxh[nt] = pb[nt];
        // issue next step's prefetch (lands during this step's compute)
#pragma unroll
        for (int nt = 0; nt < 4; ++nt)
            pa[nt] = *reinterpret_cast<const us4*>(
                &xzh[((size_t)tn * 768 + w * 64 + nt * 16 + c16) * 128 + bbase]);
#pragma unroll
        for (int nt = 0; nt < 2; ++nt)
            pb[nt] = *reinterpret_cast<const us4*>(
                &xzh[((size_t)tn * 768 + 512 + w * 32 + nt * 16 + c16) * 128 + bbase]);

        // ---- phase A: z = xz + h @ U_zr  (cols w*64 .. w*64+63) ----
        f32x4 acc[4];
#pragma unroll
        for (int nt = 0; nt < 4; ++nt) {
            acc[nt][0] = bf2f(ca[nt][0]); acc[nt][1] = bf2f(ca[nt][1]);
            acc[nt][2] = bf2f(ca[nt][2]); acc[nt][3] = bf2f(ca[nt][3]);
        }
#pragma unroll
        for (int kk = 0; kk < 8; ++kk) {
            bfrag af = __builtin_bit_cast(bfrag,
                *reinterpret_cast<const us8*>(&hb[c16 * HBP + kk * 32 + q * 8]));
#pragma unroll
            for (int nt = 0; nt < 4; ++nt)
                acc[nt] = __builtin_amdgcn_mfma_f32_16x16x32_bf16(
                    af, __builtin_bit_cast(bfrag, wA[nt][kk]), acc[nt], 0, 0, 0);
        }
        // gates: waves 0-3 -> Z (cols 0..255); waves 4-7 -> R (cols 256..511)
        if (w < 4) {
#pragma unroll
            for (int nt = 0; nt < 4; ++nt) {
                int c = w * 64 + nt * 16 + c16;
#pragma unroll
                for (int i = 0; i < 4; ++i) {
                    int r = q * 4 + i;
                    zf[r * HFP + c] = sigm(acc[nt][i]);
                }
            }
        } else {
#pragma unroll
            for (int nt = 0; nt < 4; ++nt) {
                int c = (w - 4) * 64 + nt * 16 + c16;
#pragma unroll
                for (int i = 0; i < 4; ++i) {
                    int r = q * 4 + i;
                    float rg = sigm(acc[nt][i]);
                    rhb[r * HBP + c] = f2bf(rg * hf[r * HFP + c]);
                }
            }
        }
        __syncthreads();

        // ---- phase B: s = tanh(xh + (R*h) @ U_h); h update ----
        f32x4 acc2[2];
#pragma unroll
        for (int nt = 0; nt < 2; ++nt) {
            acc2[nt][0] = bf2f(cxh[nt][0]); acc2[nt][1] = bf2f(cxh[nt][1]);
            acc2[nt][2] = bf2f(cxh[nt][2]); acc2[nt][3] = bf2f(cxh[nt][3]);
        }
#pragma unroll
        for (int kk = 0; kk < 8; ++kk) {
            bfrag rf = __builtin_bit_cast(bfrag,
                *reinterpret_cast<const us8*>(&rhb[c16 * HBP + kk * 32 + q * 8]));
#pragma unroll
            for (int nt = 0; nt < 2; ++nt)
                acc2[nt] = __builtin_amdgcn_mfma_f32_16x16x32_bf16(
                    rf, __builtin_bit_cast(bfrag, wB[nt][kk]), acc2[nt], 0, 0, 0);
        }
#pragma unroll
        for (int nt = 0; nt < 2; ++nt) {
            int c = w * 32 + nt * 16 + c16;
#pragma unroll
            for (int i = 0; i < 4; ++i) {
                int r = q * 4 + i;
                float s = tanh_(acc2[nt][i]);
                float z = zf[r * HFP + c];
                float hn = (1.0f - z) * hf[r * HFP + c] + z * s;
                hf[r * HFP + c] = hn;
                hb[r * HBP + c] = f2bf(hn);
            }
        }
        __syncthreads();
    }

    // ---- write h_last ----
    for (int i = tid; i < 16 * 256; i += 512) {
        int r = i >> 8, c = i & 255;
        out[(size_t)(g * 16 + r) * 256 + c] = hf[r * HFP + c];
    }
}

extern "C" void kernel_launch(void* const* d_in, const int* in_sizes, int n_in,
                              void* d_out, int out_size, void* d_ws, size_t ws_size,
                              hipStream_t stream) {
    const float* x   = (const float*)d_in[0];
    const float* Wzr = (const float*)d_in[1];
    const float* Uzr = (const float*)d_in[2];
    const float* bzr = (const float*)d_in[3];
    const float* Wh  = (const float*)d_in[4];
    const float* Uh  = (const float*)d_in[5];
    const float* bh  = (const float*)d_in[6];
    float* out = (float*)d_out;

    // ws: xzh bf16 [T][768][B] = 1024*768*128*2 = 201326592 bytes
    unsigned short* xzh = (unsigned short*)d_ws;

    proj_kernel<<<dim3(2048, 12), dim3(256), 0, stream>>>(x, Wzr, bzr, Wh, bh, xzh);
    gru_rec<<<dim3(8), dim3(512), 0, stream>>>(Uzr, Uh, xzh, out);
}

// Round 2
// 2313.835 us; speedup vs baseline: 2.1360x; 2.1360x over previous
//
#include <hip/hip_runtime.h>
#include <hip/hip_bf16.h>
#include <cstdint>
#include <cstddef>

#define B_ 128
#define T_ 1024
#define D_ 256
#define U_ 256

typedef __bf16 bfrag __attribute__((ext_vector_type(8)));
typedef unsigned short us8 __attribute__((ext_vector_type(8)));
typedef unsigned short us4 __attribute__((ext_vector_type(4)));
typedef float f32x4 __attribute__((ext_vector_type(4)));

__device__ __forceinline__ unsigned short f2bf(float f) {
    unsigned int u = __builtin_bit_cast(unsigned int, f);
    unsigned int r = (u + 0x7fffu + ((u >> 16) & 1u)) >> 16;
    return (unsigned short)r;
}
__device__ __forceinline__ float bf2f(unsigned short h) {
    unsigned int u = ((unsigned int)h) << 16;
    return __builtin_bit_cast(float, u);
}

#if __has_builtin(__builtin_amdgcn_exp2f)
__device__ __forceinline__ float fexp2(float x) { return __builtin_amdgcn_exp2f(x); }
#else
__device__ __forceinline__ float fexp2(float x) { return exp2f(x); }
#endif
#if __has_builtin(__builtin_amdgcn_rcpf)
__device__ __forceinline__ float frcp(float x) { return __builtin_amdgcn_rcpf(x); }
#else
__device__ __forceinline__ float frcp(float x) { return 1.0f / x; }
#endif

__device__ __forceinline__ float sigm(float x) {
    return frcp(1.0f + fexp2(-1.4426950408889634f * x));
}
__device__ __forceinline__ float tanh_(float x) {
    return 1.0f - 2.0f * frcp(1.0f + fexp2(2.8853900817779268f * x));
}

// lgkm-only barrier: LDS writes visible, but in-flight global loads NOT drained
#define BARRIER_LGKM() asm volatile("s_waitcnt lgkmcnt(0)\n\ts_barrier" ::: "memory")

// xzh layout: [t][g(8)][col(768)][b_local(16)] bf16.  col<512: xz+b_zr; col>=512: xh+b_h
#define TSTR (8 * 768 * 16)  // shorts per timestep

// ---------------------------------------------------------------------------
// proj: xzh = x @ [W_zr | W_h] + bias, bf16.
// Block = 256 thr (4 waves), BM=64 rows (16 b x 4 t), full N=768 (12 chunks
// of 64), K=256. A staged to LDS once; A-fragments held in registers across
// all chunks. W chunk staged to LDS per chunk via coalesced loads +
// register-collect transpose (b128 writes).
// ---------------------------------------------------------------------------
#define LP 264  // LDS row pad (shorts), multiple of 8

__global__ __launch_bounds__(256) void proj_kernel(
    const float* __restrict__ x, const float* __restrict__ Wzr,
    const float* __restrict__ bzr, const float* __restrict__ Wh,
    const float* __restrict__ bh, unsigned short* __restrict__ xzh)
{
    const int tid  = threadIdx.x;
    const int lane = tid & 63;
    const int wv   = tid >> 6;   // 0..3
    const int q    = lane >> 4;
    const int c16  = lane & 15;

    const int bx = blockIdx.x;
    const int bb = bx >> 8;      // batch block (16 b)
    const int tb = bx & 255;     // time block (4 t)

    __shared__ __align__(16) unsigned short ldsA[64 * LP];  // [m][k]
    __shared__ __align__(16) unsigned short ldsW[64 * LP];  // [c_local][k]

    // ---- stage A (64 rows x 256 k) once ----
    {
        const int row = tid >> 2;          // 0..63 : b = row&15, t4 = row>>4
        const int ks  = (tid & 3) * 64;
        const float* xrow = x + (((size_t)(bb * 16 + (row & 15))) * T_ + tb * 4 + (row >> 4)) * D_;
#pragma unroll
        for (int c8 = 0; c8 < 8; ++c8) {
            us8 v;
            const float* s = xrow + ks + c8 * 8;
#pragma unroll
            for (int j = 0; j < 8; ++j) v[j] = f2bf(s[j]);
            *reinterpret_cast<us8*>(&ldsA[row * LP + ks + c8 * 8]) = v;
        }
    }
    __syncthreads();

    // ---- A fragments to registers: rows (wv>>1)*32 + m2*16 + c16 ----
    const int R0 = (wv >> 1) * 32;
    us8 af[2][8];
#pragma unroll
    for (int m2 = 0; m2 < 2; ++m2)
#pragma unroll
        for (int kk = 0; kk < 8; ++kk)
            af[m2][kk] = *reinterpret_cast<const us8*>(
                &ldsA[(R0 + m2 * 16 + c16) * LP + kk * 32 + q * 8]);

    const int CW = (wv & 1) * 32;  // col base within chunk for this wave

    for (int ch = 0; ch < 12; ++ch) {
        __syncthreads();  // prev chunk's reads done before overwriting ldsW
        // ---- stage W chunk [64 cols x 256 k] transposed to [c][k] ----
        {
            const int cl = tid & 63;
            const int kg = tid >> 6;  // 0..3
            const int gc = ch * 64 + cl;
            const float* Wp; int ldw, cc;
            if (ch < 8) { Wp = Wzr; ldw = 512; cc = gc; }
            else        { Wp = Wh;  ldw = 256; cc = gc - 512; }
#pragma unroll
            for (int kb = 0; kb < 4; ++kb) {
                const int k0 = kb * 64 + kg * 16;
                float tmp[16];
#pragma unroll
                for (int p = 0; p < 16; ++p) tmp[p] = Wp[(size_t)(k0 + p) * ldw + cc];
                us8 v0, v1;
#pragma unroll
                for (int j = 0; j < 8; ++j) { v0[j] = f2bf(tmp[j]); v1[j] = f2bf(tmp[8 + j]); }
                *reinterpret_cast<us8*>(&ldsW[cl * LP + k0]) = v0;
                *reinterpret_cast<us8*>(&ldsW[cl * LP + k0 + 8]) = v1;
            }
        }
        __syncthreads();

        // ---- compute 32x32 wave tile ----
        f32x4 acc[2][2] = {};
#pragma unroll
        for (int kk = 0; kk < 8; ++kk) {
            us8 wf0 = *reinterpret_cast<const us8*>(&ldsW[(CW + c16) * LP + kk * 32 + q * 8]);
            us8 wf1 = *reinterpret_cast<const us8*>(&ldsW[(CW + 16 + c16) * LP + kk * 32 + q * 8]);
#pragma unroll
            for (int m2 = 0; m2 < 2; ++m2) {
                acc[m2][0] = __builtin_amdgcn_mfma_f32_16x16x32_bf16(
                    __builtin_bit_cast(bfrag, af[m2][kk]), __builtin_bit_cast(bfrag, wf0),
                    acc[m2][0], 0, 0, 0);
                acc[m2][1] = __builtin_amdgcn_mfma_f32_16x16x32_bf16(
                    __builtin_bit_cast(bfrag, af[m2][kk]), __builtin_bit_cast(bfrag, wf1),
                    acc[m2][1], 0, 0, 0);
            }
        }

        // ---- epilogue ----
#pragma unroll
        for (int n2 = 0; n2 < 2; ++n2) {
            const int gcn = ch * 64 + CW + n2 * 16 + c16;
            const float bias = (gcn < 512) ? bzr[gcn] : bh[gcn - 512];
#pragma unroll
            for (int m2 = 0; m2 < 2; ++m2) {
                const int t = tb * 4 + (wv >> 1) * 2 + m2;
                us4 ov;
#pragma unroll
                for (int i = 0; i < 4; ++i) ov[i] = f2bf(acc[m2][n2][i] + bias);
                *reinterpret_cast<us4*>(
                    &xzh[(((size_t)t * 8 + bb) * 768 + gcn) * 16 + q * 4]) = ov;
            }
        }
    }
}

// ---------------------------------------------------------------------------
// gru_rec: 8 WGs x 512 thr (8 waves). WG g owns batch rows [g*16, g*16+16).
// Wave w owns out-cols: phase A Z cols w*32+{0,16}+c16 and R cols
// 256+w*32+{0,16}+c16; phase B cols w*32+{0,16}+c16 (same as Z/h cols).
// h, Z in registers. LDS: only bf16 shadows hb (h) and rhb (R*h), written
// as packed dwords using a k-permutation (p = 2*(o&15) + (o>>4) within each
// 32-col block); weight fragments loaded with the matching k-remap.
// Raw lgkm-barriers; xz/xh prefetched one full step ahead.
// ---------------------------------------------------------------------------
#define HBP 264  // shorts per row

__global__ __launch_bounds__(512, 2) void gru_rec(
    const float* __restrict__ Uzr, const float* __restrict__ Uh,
    const unsigned short* __restrict__ xzh, float* __restrict__ out)
{
    const int tid  = threadIdx.x;
    const int lane = tid & 63;
    const int w    = tid >> 6;   // 0..7
    const int q    = lane >> 4;
    const int c16  = lane & 15;
    const int g    = blockIdx.x;

    __shared__ __align__(16) unsigned short hb[16 * HBP];
    __shared__ __align__(16) unsigned short rhb[16 * HBP];

    // ---- weight preload with k-perm remap: position p=kk*32+q*8+j holds
    //      original h-row kr = kk*32 + q*4 + (j>>1) + 16*(j&1) ----
    us8 wA[4][8];
#pragma unroll
    for (int nt = 0; nt < 4; ++nt) {
        const int col = (nt < 2) ? (w * 32 + nt * 16 + c16)
                                 : (256 + w * 32 + (nt - 2) * 16 + c16);
#pragma unroll
        for (int kk = 0; kk < 8; ++kk) {
            us8 v;
#pragma unroll
            for (int j = 0; j < 8; ++j) {
                const int kr = kk * 32 + q * 4 + (j >> 1) + 16 * (j & 1);
                v[j] = f2bf(Uzr[(size_t)kr * 512 + col]);
            }
            wA[nt][kk] = v;
        }
    }
    us8 wB[2][8];
#pragma unroll
    for (int nt = 0; nt < 2; ++nt) {
        const int col = w * 32 + nt * 16 + c16;
#pragma unroll
        for (int kk = 0; kk < 8; ++kk) {
            us8 v;
#pragma unroll
            for (int j = 0; j < 8; ++j) {
                const int kr = kk * 32 + q * 4 + (j >> 1) + 16 * (j & 1);
                v[j] = f2bf(Uh[(size_t)kr * 256 + col]);
            }
            wB[nt][kk] = v;
        }
    }

    for (int i = tid; i < 16 * HBP; i += 512) { hb[i] = 0; rhb[i] = 0; }
    __syncthreads();

    float hreg[2][4] = {{0, 0, 0, 0}, {0, 0, 0, 0}};

    // per-lane xzh base offsets (shorts)
    size_t laneA[4], laneB[2];
#pragma unroll
    for (int nt = 0; nt < 4; ++nt) {
        const int col = (nt < 2) ? (w * 32 + nt * 16 + c16)
                                 : (256 + w * 32 + (nt - 2) * 16 + c16);
        laneA[nt] = ((size_t)g * 768 + col) * 16 + q * 4;
    }
#pragma unroll
    for (int nt = 0; nt < 2; ++nt)
        laneB[nt] = ((size_t)g * 768 + 512 + w * 32 + nt * 16 + c16) * 16 + q * 4;

    // prefetch t=0
    us4 ca[4], cxh[2];
#pragma unroll
    for (int nt = 0; nt < 4; ++nt)
        ca[nt] = *reinterpret_cast<const us4*>(&xzh[laneA[nt]]);
#pragma unroll
    for (int nt = 0; nt < 2; ++nt)
        cxh[nt] = *reinterpret_cast<const us4*>(&xzh[laneB[nt]]);

    size_t toff = TSTR;  // points at t+1 data

    const int dwi = w * 32 + 2 * c16;  // packed-dword short index within row

#pragma unroll 1
    for (int t = 0; t < T_; ++t) {
        // issue next step's prefetch (lands any time before end of step)
        us4 na[4], nxh[2];
#pragma unroll
        for (int nt = 0; nt < 4; ++nt)
            na[nt] = *reinterpret_cast<const us4*>(&xzh[laneA[nt] + toff]);
#pragma unroll
        for (int nt = 0; nt < 2; ++nt)
            nxh[nt] = *reinterpret_cast<const us4*>(&xzh[laneB[nt] + toff]);
        if (t < 1022) toff += TSTR;

        // ---- phase A: z = xz + h @ U_zr ----
        f32x4 acc[4];
#pragma unroll
        for (int nt = 0; nt < 4; ++nt) {
            acc[nt][0] = bf2f(ca[nt][0]); acc[nt][1] = bf2f(ca[nt][1]);
            acc[nt][2] = bf2f(ca[nt][2]); acc[nt][3] = bf2f(ca[nt][3]);
        }
#pragma unroll
        for (int kk = 0; kk < 8; ++kk) {
            bfrag af = __builtin_bit_cast(bfrag,
                *reinterpret_cast<const us8*>(&hb[c16 * HBP + kk * 32 + q * 8]));
#pragma unroll
            for (int nt = 0; nt < 4; ++nt)
                acc[nt] = __builtin_amdgcn_mfma_f32_16x16x32_bf16(
                    af, __builtin_bit_cast(bfrag, wA[nt][kk]), acc[nt], 0, 0, 0);
        }
        // Z stays in regs; R -> R*h -> rhb (packed dword)
        float zreg[2][4];
#pragma unroll
        for (int i = 0; i < 4; ++i) {
            zreg[0][i] = sigm(acc[0][i]);
            zreg[1][i] = sigm(acc[1][i]);
            const float r0 = sigm(acc[2][i]);
            const float r1 = sigm(acc[3][i]);
            const unsigned int pk = (unsigned int)f2bf(r0 * hreg[0][i]) |
                                    ((unsigned int)f2bf(r1 * hreg[1][i]) << 16);
            *reinterpret_cast<unsigned int*>(&rhb[(q * 4 + i) * HBP + dwi]) = pk;
        }
        BARRIER_LGKM();

        // ---- phase B: s = tanh(xh + (R*h) @ U_h); h update ----
        f32x4 acc2[2];
#pragma unroll
        for (int nt = 0; nt < 2; ++nt) {
            acc2[nt][0] = bf2f(cxh[nt][0]); acc2[nt][1] = bf2f(cxh[nt][1]);
            acc2[nt][2] = bf2f(cxh[nt][2]); acc2[nt][3] = bf2f(cxh[nt][3]);
        }
#pragma unroll
        for (int kk = 0; kk < 8; ++kk) {
            bfrag rf = __builtin_bit_cast(bfrag,
                *reinterpret_cast<const us8*>(&rhb[c16 * HBP + kk * 32 + q * 8]));
#pragma unroll
            for (int nt = 0; nt < 2; ++nt)
                acc2[nt] = __builtin_amdgcn_mfma_f32_16x16x32_bf16(
                    rf, __builtin_bit_cast(bfrag, wB[nt][kk]), acc2[nt], 0, 0, 0);
        }
#pragma unroll
        for (int i = 0; i < 4; ++i) {
            const float s0 = tanh_(acc2[0][i]);
            const float s1 = tanh_(acc2[1][i]);
            const float h0 = hreg[0][i] + zreg[0][i] * (s0 - hreg[0][i]);
            const float h1 = hreg[1][i] + zreg[1][i] * (s1 - hreg[1][i]);
            hreg[0][i] = h0; hreg[1][i] = h1;
            const unsigned int pk = (unsigned int)f2bf(h0) |
                                    ((unsigned int)f2bf(h1) << 16);
            *reinterpret_cast<unsigned int*>(&hb[(q * 4 + i) * HBP + dwi]) = pk;
        }
        // rotate prefetch
#pragma unroll
        for (int nt = 0; nt < 4; ++nt) ca[nt] = na[nt];
#pragma unroll
        for (int nt = 0; nt < 2; ++nt) cxh[nt] = nxh[nt];
        BARRIER_LGKM();
    }

    // ---- write h_last ----
#pragma unroll
    for (int nt = 0; nt < 2; ++nt)
#pragma unroll
        for (int i = 0; i < 4; ++i)
            out[(size_t)(g * 16 + q * 4 + i) * 256 + w * 32 + nt * 16 + c16] = hreg[nt][i];
}

extern "C" void kernel_launch(void* const* d_in, const int* in_sizes, int n_in,
                              void* d_out, int out_size, void* d_ws, size_t ws_size,
                              hipStream_t stream) {
    const float* x   = (const float*)d_in[0];
    const float* Wzr = (const float*)d_in[1];
    const float* Uzr = (const float*)d_in[2];
    const float* bzr = (const float*)d_in[3];
    const float* Wh  = (const float*)d_in[4];
    const float* Uh  = (const float*)d_in[5];
    const float* bh  = (const float*)d_in[6];
    float* out = (float*)d_out;

    unsigned short* xzh = (unsigned short*)d_ws;  // [T][8][768][16] bf16 = 201.3 MB

    proj_kernel<<<dim3(2048), dim3(256), 0, stream>>>(x, Wzr, bzr, Wh, bh, xzh);
    gru_rec<<<dim3(8), dim3(512), 0, stream>>>(Uzr, Uh, xzh, out);
}